// Round 11
// baseline (387.400 us; speedup 1.0000x reference)
//
#include <hip/hip_runtime.h>
#include <stdint.h>

typedef unsigned short u16;

#define BB 2
#define NN 2048
#define MM 2048
#define CC 512
#define KK 16
#define KK1 8
#define KEY 1024

typedef __attribute__((ext_vector_type(8))) short bf16x8;
typedef __attribute__((ext_vector_type(4))) float f32x4;

__device__ __forceinline__ float b2f(u16 u){ return __uint_as_float(((uint32_t)u) << 16); }
__device__ __forceinline__ u16 f2b(float f){
  uint32_t x = __float_as_uint(f);
  uint32_t r = x + 0x7FFFu + ((x >> 16) & 1u);
  return (u16)(r >> 16);
}
__device__ __forceinline__ float sane(float v){ return (fabsf(v) < 1e30f) ? v : 1e30f; }

// all-thread block reduction, 256 threads. op: 0=sum 1=min 2=max
__device__ __forceinline__ float blockRed(float v, float* red, int t, int op){
  red[t] = v; __syncthreads();
  #pragma unroll
  for (int s = 128; s > 0; s >>= 1){
    if (t < s){
      float a = red[t], b = red[t + s];
      red[t] = (op == 0) ? (a + b) : ((op == 1) ? fminf(a, b) : fmaxf(a, b));
    }
    __syncthreads();
  }
  float r = red[0]; __syncthreads();
  return r;
}

// ---- K0: transpose f32 (B,C,N) -> split-bf16 (B,N,C) hi/lo pairs -------------------
__global__ __launch_bounds__(256) void k_trans(const float* __restrict__ semb, const float* __restrict__ temb,
                                               u16* __restrict__ Ah, u16* __restrict__ Al,
                                               u16* __restrict__ Bh, u16* __restrict__ Bl){
  __shared__ float tile[32][33];
  int b = blockIdx.z & 1, which = blockIdx.z >> 1;
  const float* in = which ? temb : semb;
  u16* oh = which ? Bh : Ah;
  u16* ol = which ? Bl : Al;
  int c0 = blockIdx.x * 32, n0 = blockIdx.y * 32;
  int tx = threadIdx.x, ty = threadIdx.y;
  #pragma unroll
  for (int i = 0; i < 4; i++){
    int r = ty + 8 * i;
    tile[r][tx] = in[((b * CC + c0 + r) * NN) + n0 + tx];
  }
  __syncthreads();
  #pragma unroll
  for (int i = 0; i < 4; i++){
    int r = ty + 8 * i;
    float v = tile[tx][r];
    u16 hi = f2b(v);
    float lo = v - b2f(hi);
    size_t o = ((size_t)(b * NN + n0 + r) * CC) + c0 + tx;
    oh[o] = hi;
    ol[o] = f2b(lo);
  }
}

// ---- K1: exact f32 row squared norms from (B,C,N) layout (coalesced over n) --------
__global__ __launch_bounds__(256) void k_sq(const float* __restrict__ semb, const float* __restrict__ temb,
                                            float* __restrict__ xx, float* __restrict__ yy){
  int which = blockIdx.y;
  const float* in = which ? temb : semb;
  float* out = which ? yy : xx;
  int gid = blockIdx.x * 256 + threadIdx.x;   // 0..4095
  int b = gid >> 11, n = gid & 2047;
  float acc = 0.f;
  for (int c = 0; c < CC; c++){
    float v = in[((size_t)(b * CC + c)) * NN + n];
    acc += v * v;
  }
  out[gid] = acc;
}

// ---- K2: dist = xx - 2*A.B^T + yy, split-bf16 MFMA (hi*hi + hi*lo + lo*hi) ---------
__global__ __launch_bounds__(256) void k_gemm(const u16* __restrict__ Ah, const u16* __restrict__ Al,
                                              const u16* __restrict__ Bh, const u16* __restrict__ Bl,
                                              const float* __restrict__ xx, const float* __restrict__ yy,
                                              float* __restrict__ dist){
  __shared__ __align__(16) u16 lAh[128 * 64];
  __shared__ __align__(16) u16 lAl[128 * 64];
  __shared__ __align__(16) u16 lBh[128 * 64];
  __shared__ __align__(16) u16 lBl[128 * 64];
  int n0 = blockIdx.y * 128, m0 = blockIdx.x * 128;
  int t = threadIdx.x;
  f32x4 acc[4][4];
  #pragma unroll
  for (int i = 0; i < 4; i++)
    #pragma unroll
    for (int j = 0; j < 4; j++){ f32x4 z = {0.f, 0.f, 0.f, 0.f}; acc[i][j] = z; }
  int w = t >> 6, lane = t & 63, lr = lane & 15, quad = lane >> 4;
  int wn = (w >> 1) * 64, wm = (w & 1) * 64;
  for (int kt = 0; kt < 8; kt++){
    int k0 = kt * 64;
    bf16x8 vah[4], val[4], vbh[4], vbl[4];
    #pragma unroll
    for (int s = 0; s < 4; s++){
      int ch = t + 256 * s;
      int rn = ch >> 3, k8 = (ch & 7) * 8;
      size_t oa = (size_t)(n0 + rn) * CC + k0 + k8;
      size_t ob = (size_t)(m0 + rn) * CC + k0 + k8;
      vah[s] = *(const bf16x8*)(Ah + oa);
      val[s] = *(const bf16x8*)(Al + oa);
      vbh[s] = *(const bf16x8*)(Bh + ob);
      vbl[s] = *(const bf16x8*)(Bl + ob);
    }
    __syncthreads();
    #pragma unroll
    for (int s = 0; s < 4; s++){
      int ch = t + 256 * s;
      *(bf16x8*)&lAh[ch * 8] = vah[s];
      *(bf16x8*)&lAl[ch * 8] = val[s];
      *(bf16x8*)&lBh[ch * 8] = vbh[s];
      *(bf16x8*)&lBl[ch * 8] = vbl[s];
    }
    __syncthreads();
    #pragma unroll
    for (int kk = 0; kk < 2; kk++){
      int off = kk * 32 + quad * 8;
      bf16x8 afh[4], afl[4], bfh[4], bfl[4];
      #pragma unroll
      for (int i = 0; i < 4; i++){
        int ra = (wn + i * 16 + lr) * 64 + off;
        afh[i] = *(const bf16x8*)&lAh[ra];
        afl[i] = *(const bf16x8*)&lAl[ra];
      }
      #pragma unroll
      for (int j = 0; j < 4; j++){
        int rb = (wm + j * 16 + lr) * 64 + off;
        bfh[j] = *(const bf16x8*)&lBh[rb];
        bfl[j] = *(const bf16x8*)&lBl[rb];
      }
      #pragma unroll
      for (int i = 0; i < 4; i++)
        #pragma unroll
        for (int j = 0; j < 4; j++){
          acc[i][j] = __builtin_amdgcn_mfma_f32_16x16x32_bf16(afh[i], bfh[j], acc[i][j], 0, 0, 0);
          acc[i][j] = __builtin_amdgcn_mfma_f32_16x16x32_bf16(afh[i], bfl[j], acc[i][j], 0, 0, 0);
          acc[i][j] = __builtin_amdgcn_mfma_f32_16x16x32_bf16(afl[i], bfh[j], acc[i][j], 0, 0, 0);
        }
    }
  }
  #pragma unroll
  for (int i = 0; i < 4; i++){
    int nbase = n0 + wn + i * 16 + quad * 4;
    #pragma unroll
    for (int j = 0; j < 4; j++){
      int m = m0 + wm + j * 16 + lr;
      float yv = yy[m];
      #pragma unroll
      for (int r = 0; r < 4; r++){
        dist[((size_t)(nbase + r)) * MM + m] = xx[nbase + r] + yv - 2.0f * acc[i][j][r];
      }
    }
  }
}

// ---- K3: per-row min & softmax(-dist) denominator ----------------------------------
__global__ __launch_bounds__(256) void k_rowstats(const float* __restrict__ dist,
                                                  float* __restrict__ mnA, float* __restrict__ Zr){
  __shared__ float red[256];
  int row = blockIdx.x, t = threadIdx.x;
  const float* dr = dist + (size_t)row * MM;
  float d[8];
  float mn = 3.4e38f;
  #pragma unroll
  for (int i = 0; i < 8; i++){ d[i] = sane(dr[t + 256 * i]); mn = fminf(mn, d[i]); }
  mn = blockRed(mn, red, t, 1);
  float z = 0.f;
  #pragma unroll
  for (int i = 0; i < 8; i++) z += expf(mn - d[i]);
  z = blockRed(z, red, t, 0);
  if (t == 0){ mnA[row] = mn; Zr[row] = fmaxf(z, 1e-30f); }
}

// ---- K4: fused T/S/refined/rmm/src_corr/loss per row n (per batch) -----------------
__global__ __launch_bounds__(256) void k_fused(const float* __restrict__ dist, const float* __restrict__ mnA,
                                               const float* __restrict__ Zr, const int* __restrict__ sidx1b,
                                               const int* __restrict__ idx2b, const float* __restrict__ tgtb,
                                               float* __restrict__ s_corrb, float* __restrict__ lossb){
  __shared__ float Trow[MM];
  __shared__ float red[256];
  int n = blockIdx.x, t = threadIdx.x;
  const float* dn_p = dist + (size_t)n * MM;
  float dn[8];
  #pragma unroll
  for (int i = 0; i < 8; i++) dn[i] = sane(dn_p[t + 256 * i]);
  float tacc[8] = {0, 0, 0, 0, 0, 0, 0, 0};
  const int* i1 = sidx1b + n * KK1;
  for (int j = 1; j < KK1; j++){
    int r = i1[j] & 2047;
    float mnj = mnA[r];
    float izj = 1.0f / Zr[r];
    const float* drp = dist + (size_t)r * MM;
    #pragma unroll
    for (int i = 0; i < 8; i++) tacc[i] += expf(mnj - sane(drp[t + 256 * i])) * izj;
  }
  #pragma unroll
  for (int i = 0; i < 8; i++) Trow[t + 256 * i] = tacc[i];
  __syncthreads();
  float rloc[8];
  float lmin = 3.4e38f;
  #pragma unroll
  for (int i = 0; i < 8; i++){
    int m = t + 256 * i;
    const int* ip = idx2b + m * KK1;
    float S = 0.f;
    #pragma unroll
    for (int j = 1; j < KK1; j++) S += Trow[ip[j] & 2047];
    float rv = sane(expf(1.0f - S / 7.0f) * dn[i]);
    rloc[i] = rv;
    lmin = fminf(lmin, rv);
  }
  float rmin = blockRed(lmin, red, t, 1);
  float z = 0.f, s0 = 0.f, s1 = 0.f, s2 = 0.f;
  #pragma unroll
  for (int i = 0; i < 8; i++){
    int m = t + 256 * i;
    float p = expf(rmin - rloc[i]);
    z  += p;
    s0 += tgtb[0 * MM + m] * p;
    s1 += tgtb[1 * MM + m] * p;
    s2 += tgtb[2 * MM + m] * p;
  }
  z  = blockRed(z,  red, t, 0);
  s0 = blockRed(s0, red, t, 0);
  s1 = blockRed(s1, red, t, 0);
  s2 = blockRed(s2, red, t, 0);
  if (t == 0){
    float iZ = 1.0f / fmaxf(z, 1e-30f);
    s_corrb[0 * NN + n] = s0 * iZ;
    s_corrb[1 * NN + n] = s1 * iZ;
    s_corrb[2 * NN + n] = s2 * iZ;
    lossb[n] = -logf(fminf(iZ, 1.0f) + 1e-15f);  // pred at onehot == rowmax(rmm) == 1/Z
  }
}

// ---- K5: discriminator MLP, scalar f32. Value path identical to R10 (which passed):
// layer-1 expressions verbatim; LDS store swizzle verbatim; the e-loop consumes
// LOGICAL chunks 0..15 in ascending order with the SAME per-q statement shape
// (a += wv.x*h.x + wv.y*h.y + wv.z*h.z + wv.w*h.w). Only change vs R10: the 16
// row chunks are hoisted into named f32x4 registers ONCE (h_j = hp[(j+t)&15] =
// logical chunk j), replacing 2048 ds_read_b128/thread with 16. R10 counters:
// VALUBusy 19%, LDS-throughput-bound (~41us of ds_read issue) -> pure-VALU loop.
__global__ __launch_bounds__(256) void k_disc(const float* __restrict__ s_corr, const float* __restrict__ src,
                                              const float* __restrict__ sknn, const int* __restrict__ sidx,
                                              const float* __restrict__ W1, const float* __restrict__ b1,
                                              const float* __restrict__ W2, const float* __restrict__ b2,
                                              const float* __restrict__ W3, const float* __restrict__ b3,
                                              float* __restrict__ sArr){
  __shared__ __align__(16) float Hs[256 * 64];   // 64 KB; per-thread-private rows
  int t = threadIdx.x;
  int b = blockIdx.z;
  int n = blockIdx.y * 16 + (t >> 4);
  int kk = t & 15;
  int nk = sidx[((b * NN + n) * KK) + kk] & 2047;
  float f[6];
  #pragma unroll
  for (int c = 0; c < 3; c++){
    f[c]     = s_corr[(b * 3 + c) * NN + n] - s_corr[(b * 3 + c) * NN + nk];
    f[3 + c] = src[(b * 3 + c) * NN + n] - sknn[((size_t)(b * NN + n) * KK + kk) * 3 + c];
  }
  // layer 1: same expressions as R10
  #pragma unroll
  for (int d = 0; d < 64; d++){
    float a = b1[d];
    #pragma unroll
    for (int c = 0; c < 6; c++) a += f[c] * W1[d * 6 + c];
    Hs[t * 64 + ((((d >> 2) + t) & 15) << 2) + (d & 3)] = fmaxf(a, 0.f);
  }
  // hoist the row into named registers: h_j = physical chunk (j+t)&15 = LOGICAL chunk j
  const f32x4* hp = (const f32x4*)&Hs[t * 64];
  #define HLOAD(i) f32x4 h##i = hp[((i) + t) & 15];
  HLOAD(0) HLOAD(1) HLOAD(2) HLOAD(3) HLOAD(4) HLOAD(5) HLOAD(6) HLOAD(7)
  HLOAD(8) HLOAD(9) HLOAD(10) HLOAD(11) HLOAD(12) HLOAD(13) HLOAD(14) HLOAD(15)
  #undef HLOAD
  float sacc = b3[0];
  for (int e = 0; e < 128; e++){
    float a = b2[e];
    const f32x4* w4 = (const f32x4*)&W2[e * 64];
    #define QSTEP(i) { f32x4 wv = w4[i]; a += wv.x * h##i.x + wv.y * h##i.y + wv.z * h##i.z + wv.w * h##i.w; }
    QSTEP(0) QSTEP(1) QSTEP(2) QSTEP(3) QSTEP(4) QSTEP(5) QSTEP(6) QSTEP(7)
    QSTEP(8) QSTEP(9) QSTEP(10) QSTEP(11) QSTEP(12) QSTEP(13) QSTEP(14) QSTEP(15)
    #undef QSTEP
    sacc += W3[e] * fmaxf(a, 0.f);
  }
  if (!(fabsf(sacc) < 1e30f)) sacc = -1e30f;
  #pragma unroll
  for (int off = 1; off < 16; off <<= 1) sacc = fmaxf(sacc, __shfl_xor(sacc, off, 16));
  if (kk == 0) sArr[b * NN + n] = sacc;
}

// ---- K6: weight = softmax(s) over n ------------------------------------------------
__global__ __launch_bounds__(256) void k_softw(const float* __restrict__ sArr, float* __restrict__ wArr){
  __shared__ float red[256];
  int b = blockIdx.x, t = threadIdx.x;
  const float* sp = sArr + b * NN;
  float sv[8];
  float mx = -3.4e38f;
  #pragma unroll
  for (int i = 0; i < 8; i++){
    float v = sp[t + 256 * i];
    if (!(fabsf(v) < 1e30f)) v = -1e30f;
    sv[i] = v; mx = fmaxf(mx, v);
  }
  mx = blockRed(mx, red, t, 2);
  float z = 0.f;
  #pragma unroll
  for (int i = 0; i < 8; i++) z += expf(sv[i] - mx);
  z = blockRed(z, red, t, 0);
  float iz = 1.0f / fmaxf(z, 1e-30f);
  #pragma unroll
  for (int i = 0; i < 8; i++) wArr[b * NN + t + 256 * i] = expf(sv[i] - mx) * iz;
}

// ---- K7: stable descending rank -> topi --------------------------------------------
__global__ __launch_bounds__(256) void k_rank(const float* __restrict__ wArr, int* __restrict__ topi){
  __shared__ float wrow[NN];
  int b = blockIdx.y, t = threadIdx.x;
  for (int i = t; i < NN; i += 256) wrow[i] = wArr[b * NN + i];
  __syncthreads();
  int n = blockIdx.x * 256 + t;
  float wn = wrow[n];
  int cnt = 0;
  for (int j = 0; j < NN; j++){
    float wj = wrow[j];
    cnt += (wj > wn) || ((wj == wn) && (j < n));
  }
  if (cnt < KEY) topi[b * KEY + cnt] = n;
}

// ---- K8: weighted centroids, H, 3x3 SVD (f64 Jacobi), R/t --------------------------
__device__ __forceinline__ double det3d(const double A[3][3]){
  return A[0][0] * (A[1][1] * A[2][2] - A[1][2] * A[2][1])
       - A[0][1] * (A[1][0] * A[2][2] - A[1][2] * A[2][0])
       + A[0][2] * (A[1][0] * A[2][1] - A[1][1] * A[2][0]);
}

__global__ __launch_bounds__(256) void k_rigid(const float* __restrict__ src, const float* __restrict__ s_corr,
                                               const float* __restrict__ wArr, float* __restrict__ Rt,
                                               float* __restrict__ out){
  __shared__ float red[256];
  int b = blockIdx.x, t = threadIdx.x;
  float wsum = 0, a0 = 0, a1 = 0, a2 = 0, c0 = 0, c1 = 0, c2 = 0;
  for (int n = t; n < NN; n += 256){
    float wv = wArr[b * NN + n];
    float s0 = src[(b * 3 + 0) * NN + n];
    float s1 = src[(b * 3 + 1) * NN + n];
    float s2 = src[(b * 3 + 2) * NN + n];
    float q0 = s_corr[(b * 3 + 0) * NN + n];
    float q1 = s_corr[(b * 3 + 1) * NN + n];
    float q2 = s_corr[(b * 3 + 2) * NN + n];
    wsum += wv; a0 += wv * s0; a1 += wv * s1; a2 += wv * s2;
    c0 += wv * q0; c1 += wv * q1; c2 += wv * q2;
  }
  wsum = blockRed(wsum, red, t, 0);
  a0 = blockRed(a0, red, t, 0); a1 = blockRed(a1, red, t, 0); a2 = blockRed(a2, red, t, 0);
  c0 = blockRed(c0, red, t, 0); c1 = blockRed(c1, red, t, 0); c2 = blockRed(c2, red, t, 0);
  float inv = 1.0f / fmaxf(wsum, 1e-30f);
  float cs0 = a0 * inv, cs1 = a1 * inv, cs2 = a2 * inv;
  float ct0 = c0 * inv, ct1 = c1 * inv, ct2 = c2 * inv;
  float h[9] = {0, 0, 0, 0, 0, 0, 0, 0, 0};
  for (int n = t; n < NN; n += 256){
    float wv = wArr[b * NN + n];
    float ds0 = src[(b * 3 + 0) * NN + n] - cs0;
    float ds1 = src[(b * 3 + 1) * NN + n] - cs1;
    float ds2 = src[(b * 3 + 2) * NN + n] - cs2;
    float dc0 = s_corr[(b * 3 + 0) * NN + n] - ct0;
    float dc1 = s_corr[(b * 3 + 1) * NN + n] - ct1;
    float dc2 = s_corr[(b * 3 + 2) * NN + n] - ct2;
    h[0] += wv * ds0 * dc0; h[1] += wv * ds0 * dc1; h[2] += wv * ds0 * dc2;
    h[3] += wv * ds1 * dc0; h[4] += wv * ds1 * dc1; h[5] += wv * ds1 * dc2;
    h[6] += wv * ds2 * dc0; h[7] += wv * ds2 * dc1; h[8] += wv * ds2 * dc2;
  }
  for (int i = 0; i < 9; i++) h[i] = blockRed(h[i], red, t, 0);
  if (t == 0){
    double Hm[3][3];
    for (int i = 0; i < 3; i++)
      for (int j = 0; j < 3; j++) Hm[i][j] = (double)h[i * 3 + j];
    double Km[3][3], V[3][3] = {{1, 0, 0}, {0, 1, 0}, {0, 0, 1}};
    for (int i = 0; i < 3; i++)
      for (int j = 0; j < 3; j++){
        double s = 0;
        for (int a = 0; a < 3; a++) s += Hm[a][i] * Hm[a][j];
        Km[i][j] = s;
      }
    double ksc = fabs(Km[0][0]) + fabs(Km[1][1]) + fabs(Km[2][2]) + 1e-300;
    for (int sweep = 0; sweep < 60; sweep++){
      int p = 0, q = 1; double mx = fabs(Km[0][1]);
      if (fabs(Km[0][2]) > mx){ mx = fabs(Km[0][2]); p = 0; q = 2; }
      if (fabs(Km[1][2]) > mx){ mx = fabs(Km[1][2]); p = 1; q = 2; }
      if (mx <= 1e-15 * ksc) break;
      double app = Km[p][p], aqq = Km[q][q], apq = Km[p][q];
      double tau = (aqq - app) / (2.0 * apq);
      double tt = ((tau >= 0) ? 1.0 : -1.0) / (fabs(tau) + sqrt(1.0 + tau * tau));
      double cc = 1.0 / sqrt(1.0 + tt * tt), sn = tt * cc;
      for (int k2 = 0; k2 < 3; k2++){
        double akp = Km[k2][p], akq = Km[k2][q];
        Km[k2][p] = cc * akp - sn * akq; Km[k2][q] = sn * akp + cc * akq;
      }
      for (int k2 = 0; k2 < 3; k2++){
        double apk = Km[p][k2], aqk = Km[q][k2];
        Km[p][k2] = cc * apk - sn * aqk; Km[q][k2] = sn * apk + cc * aqk;
      }
      for (int k2 = 0; k2 < 3; k2++){
        double vkp = V[k2][p], vkq = V[k2][q];
        V[k2][p] = cc * vkp - sn * vkq; V[k2][q] = sn * vkp + cc * vkq;
      }
    }
    double lam[3] = {Km[0][0], Km[1][1], Km[2][2]};
    int id0 = 0, id1 = 1, id2 = 2, tmp;
    if (lam[id0] < lam[id1]){ tmp = id0; id0 = id1; id1 = tmp; }
    if (lam[id0] < lam[id2]){ tmp = id0; id0 = id2; id2 = tmp; }
    if (lam[id1] < lam[id2]){ tmp = id1; id1 = id2; id2 = tmp; }
    int idx[3] = {id0, id1, id2};
    double Vs[3][3], U[3][3] = {{0, 0, 0}, {0, 0, 0}, {0, 0, 0}};
    for (int jj = 0; jj < 3; jj++){
      int j = idx[jj];
      for (int i2 = 0; i2 < 3; i2++) Vs[i2][jj] = V[i2][j];
      double u0 = 0, u1 = 0, u2 = 0;
      for (int i2 = 0; i2 < 3; i2++){
        u0 += Hm[0][i2] * V[i2][j];
        u1 += Hm[1][i2] * V[i2][j];
        u2 += Hm[2][i2] * V[i2][j];
      }
      double nrm = sqrt(u0 * u0 + u1 * u1 + u2 * u2);
      if (nrm > 1e-20){
        U[0][jj] = u0 / nrm; U[1][jj] = u1 / nrm; U[2][jj] = u2 / nrm;
      } else {
        double x0 = U[1][0] * U[2][1] - U[2][0] * U[1][1];
        double x1 = U[2][0] * U[0][1] - U[0][0] * U[2][1];
        double x2 = U[0][0] * U[1][1] - U[1][0] * U[0][1];
        double nn2 = sqrt(x0 * x0 + x1 * x1 + x2 * x2);
        if (nn2 < 1e-20){ x0 = 1; x1 = 0; x2 = 0; nn2 = 1; }
        U[0][jj] = x0 / nn2; U[1][jj] = x1 / nn2; U[2][jj] = x2 / nn2;
      }
    }
    double dd = det3d(U) * det3d(Vs);
    double Rm[3][3];
    for (int i2 = 0; i2 < 3; i2++)
      for (int k2 = 0; k2 < 3; k2++)
        Rm[i2][k2] = Vs[i2][0] * U[k2][0] + Vs[i2][1] * U[k2][1] + dd * Vs[i2][2] * U[k2][2];
    double cs[3] = {cs0, cs1, cs2}, ct[3] = {ct0, ct1, ct2};
    double tv[3];
    for (int i2 = 0; i2 < 3; i2++)
      tv[i2] = ct[i2] - (Rm[i2][0] * cs[0] + Rm[i2][1] * cs[1] + Rm[i2][2] * cs[2]);
    for (int i2 = 0; i2 < 3; i2++)
      for (int k2 = 0; k2 < 3; k2++){
        Rt[b * 12 + i2 * 3 + k2] = (float)Rm[i2][k2];
        out[b * 9 + i2 * 3 + k2] = (float)Rm[i2][k2];
      }
    for (int i2 = 0; i2 < 3; i2++){
      Rt[b * 12 + 9 + i2] = (float)tv[i2];
      out[18 + b * 3 + i2] = (float)tv[i2];
    }
  }
}

// ---- K9: src_transformed = R*src + t -----------------------------------------------
__global__ __launch_bounds__(256) void k_st(const float* __restrict__ src, const float* __restrict__ Rt,
                                            float* __restrict__ st){
  int id = blockIdx.x * 256 + threadIdx.x;
  int b = id >> 11, n = id & 2047;
  float s0 = src[(b * 3 + 0) * NN + n];
  float s1 = src[(b * 3 + 1) * NN + n];
  float s2 = src[(b * 3 + 2) * NN + n];
  const float* R = Rt + b * 12;
  #pragma unroll
  for (int c = 0; c < 3; c++)
    st[(b * 3 + c) * NN + n] = R[c * 3 + 0] * s0 + R[c * 3 + 1] * s1 + R[c * 3 + 2] * s2 + R[9 + c];
}

// ---- K10: gather keypoint outputs (float32 out) ------------------------------------
__global__ __launch_bounds__(256) void k_out(const int* __restrict__ topi, const int* __restrict__ sidx,
                                             const float* __restrict__ src, const float* __restrict__ s_corr,
                                             const float* __restrict__ st, float* __restrict__ out){
  int b = blockIdx.y, t = threadIdx.x;
  int rr = t >> 4, kk = t & 15;
  int r = blockIdx.x * 16 + rr;
  int ns = topi[b * KEY + r] & 2047;
  int nk = sidx[(b * NN + ns) * KK + kk] & 2047;
  float* o_sk  = out + 24;
  float* o_tk  = out + 6168;
  float* o_skk = out + 12312;
  float* o_tkk = out + 110616;
  #pragma unroll
  for (int c = 0; c < 3; c++){
    float cv  = s_corr[(b * 3 + c) * NN + ns];
    float ck  = s_corr[(b * 3 + c) * NN + nk];
    o_tkk[(((b * 3 + c) * KEY + r) * KK) + kk] = cv - ck;
    float sv  = st[(b * 3 + c) * NN + ns];
    float sk2 = st[(b * 3 + c) * NN + nk];
    o_skk[(((b * 3 + c) * KEY + r) * KK) + kk] = sv - sk2;
    if (kk == 0){
      o_sk[(b * 3 + c) * KEY + r] = src[(b * 3 + c) * NN + ns];
      o_tk[(b * 3 + c) * KEY + r] = cv;
    }
  }
}

// ---- K11: loss_scl -----------------------------------------------------------------
__global__ __launch_bounds__(256) void k_loss(const float* __restrict__ loss_row, const int* __restrict__ topi,
                                              float* __restrict__ out){
  __shared__ float red[256];
  int t = threadIdx.x;
  float acc = 0.f;
  for (int i = t; i < BB * KEY; i += 256){
    int b = i >> 10, r = i & 1023;
    int n = topi[b * KEY + r] & 2047;
    acc += loss_row[b * NN + n];
  }
  acc = blockRed(acc, red, t, 0);
  if (t == 0) out[208920] = acc / 2048.0f;
}

extern "C" void kernel_launch(void* const* d_in, const int* in_sizes, int n_in,
                              void* d_out, int out_size, void* d_ws, size_t ws_size,
                              hipStream_t stream){
  const float* src  = (const float*)d_in[0];
  const float* tgt  = (const float*)d_in[1];
  const float* semb = (const float*)d_in[2];
  const float* temb = (const float*)d_in[3];
  const float* sknn = (const float*)d_in[4];
  const float* W1 = (const float*)d_in[6];
  const float* b1 = (const float*)d_in[7];
  const float* W2 = (const float*)d_in[8];
  const float* b2 = (const float*)d_in[9];
  const float* W3 = (const float*)d_in[10];
  const float* b3 = (const float*)d_in[11];
  const int* sidx  = (const int*)d_in[12];
  const int* sidx1 = (const int*)d_in[13];
  const int* idx2  = (const int*)d_in[14];
  float* out = (float*)d_out;

  // workspace layout (peak ~33.4 MB)
  char* w = (char*)d_ws;
  u16* Ah = (u16*)(w);                               // 4 MB each (B,N,C) bf16 split
  u16* Al = Ah + (size_t)BB * NN * CC;
  u16* Bh = Al + (size_t)BB * NN * CC;
  u16* Bl = Bh + (size_t)BB * MM * CC;
  float* dist = (float*)(Bl + (size_t)BB * MM * CC); // 16.78 MB (N,M) f32, per-batch reuse
  char* tail = (char*)(dist + (size_t)NN * MM);
  float* xx = (float*)tail;                          // B*N
  float* yy = xx + BB * NN;                          // B*M
  float* mnA = yy + BB * MM;                         // B*N
  float* Zr = mnA + BB * NN;                         // B*N
  float* s_corr = Zr + BB * NN;                      // B*3*N
  float* loss_row = s_corr + BB * 3 * NN;            // B*N
  float* sArr = loss_row + BB * NN;                  // B*N
  float* wArr = sArr + BB * NN;                      // B*N
  int* topi = (int*)(wArr + BB * NN);                // B*KEY
  float* Rt = (float*)(topi + BB * KEY);             // B*12
  float* st = Rt + BB * 16;                          // B*3*N

  k_trans<<<dim3(16, 64, 4), dim3(32, 8), 0, stream>>>(semb, temb, Ah, Al, Bh, Bl);
  k_sq<<<dim3(16, 2), 256, 0, stream>>>(semb, temb, xx, yy);
  for (int b = 0; b < BB; b++){
    k_gemm<<<dim3(16, 16), 256, 0, stream>>>(Ah + (size_t)b * NN * CC, Al + (size_t)b * NN * CC,
                                             Bh + (size_t)b * MM * CC, Bl + (size_t)b * MM * CC,
                                             xx + b * NN, yy + b * MM, dist);
    k_rowstats<<<NN, 256, 0, stream>>>(dist, mnA + b * NN, Zr + b * NN);
    k_fused<<<NN, 256, 0, stream>>>(dist, mnA + b * NN, Zr + b * NN,
                                    sidx1 + (size_t)b * NN * KK1, idx2 + (size_t)b * MM * KK1,
                                    tgt + (size_t)b * 3 * MM, s_corr + (size_t)b * 3 * NN,
                                    loss_row + b * NN);
  }
  k_disc<<<dim3(1, 128, 2), 256, 0, stream>>>(s_corr, src, sknn, sidx, W1, b1, W2, b2, W3, b3, sArr);
  k_softw<<<BB, 256, 0, stream>>>(sArr, wArr);
  k_rank<<<dim3(8, BB), 256, 0, stream>>>(wArr, topi);
  k_rigid<<<BB, 256, 0, stream>>>(src, s_corr, wArr, Rt, out);
  k_st<<<16, 256, 0, stream>>>(src, Rt, st);
  k_out<<<dim3(64, BB), 256, 0, stream>>>(topi, sidx, src, s_corr, st, out);
  k_loss<<<1, 256, 0, stream>>>(loss_row, topi, out);
}

// Round 12
// 383.039 us; speedup vs baseline: 1.0114x; 1.0114x over previous
//
#include <hip/hip_runtime.h>
#include <stdint.h>

typedef unsigned short u16;

#define BB 2
#define NN 2048
#define MM 2048
#define CC 512
#define KK 16
#define KK1 8
#define KEY 1024

typedef __attribute__((ext_vector_type(8))) short bf16x8;
typedef __attribute__((ext_vector_type(4))) float f32x4;

__device__ __forceinline__ float b2f(u16 u){ return __uint_as_float(((uint32_t)u) << 16); }
__device__ __forceinline__ u16 f2b(float f){
  uint32_t x = __float_as_uint(f);
  uint32_t r = x + 0x7FFFu + ((x >> 16) & 1u);
  return (u16)(r >> 16);
}
__device__ __forceinline__ float sane(float v){ return (fabsf(v) < 1e30f) ? v : 1e30f; }

// all-thread block reduction, 256 threads. op: 0=sum 1=min 2=max
__device__ __forceinline__ float blockRed(float v, float* red, int t, int op){
  red[t] = v; __syncthreads();
  #pragma unroll
  for (int s = 128; s > 0; s >>= 1){
    if (t < s){
      float a = red[t], b = red[t + s];
      red[t] = (op == 0) ? (a + b) : ((op == 1) ? fminf(a, b) : fmaxf(a, b));
    }
    __syncthreads();
  }
  float r = red[0]; __syncthreads();
  return r;
}

// ---- K0: transpose f32 (B,C,N) -> split-bf16 (B,N,C) hi/lo pairs -------------------
__global__ __launch_bounds__(256) void k_trans(const float* __restrict__ semb, const float* __restrict__ temb,
                                               u16* __restrict__ Ah, u16* __restrict__ Al,
                                               u16* __restrict__ Bh, u16* __restrict__ Bl){
  __shared__ float tile[32][33];
  int b = blockIdx.z & 1, which = blockIdx.z >> 1;
  const float* in = which ? temb : semb;
  u16* oh = which ? Bh : Ah;
  u16* ol = which ? Bl : Al;
  int c0 = blockIdx.x * 32, n0 = blockIdx.y * 32;
  int tx = threadIdx.x, ty = threadIdx.y;
  #pragma unroll
  for (int i = 0; i < 4; i++){
    int r = ty + 8 * i;
    tile[r][tx] = in[((b * CC + c0 + r) * NN) + n0 + tx];
  }
  __syncthreads();
  #pragma unroll
  for (int i = 0; i < 4; i++){
    int r = ty + 8 * i;
    float v = tile[tx][r];
    u16 hi = f2b(v);
    float lo = v - b2f(hi);
    size_t o = ((size_t)(b * NN + n0 + r) * CC) + c0 + tx;
    oh[o] = hi;
    ol[o] = f2b(lo);
  }
}

// ---- K1: exact f32 row squared norms from (B,C,N) layout (coalesced over n) --------
__global__ __launch_bounds__(256) void k_sq(const float* __restrict__ semb, const float* __restrict__ temb,
                                            float* __restrict__ xx, float* __restrict__ yy){
  int which = blockIdx.y;
  const float* in = which ? temb : semb;
  float* out = which ? yy : xx;
  int gid = blockIdx.x * 256 + threadIdx.x;   // 0..4095
  int b = gid >> 11, n = gid & 2047;
  float acc = 0.f;
  for (int c = 0; c < CC; c++){
    float v = in[((size_t)(b * CC + c)) * NN + n];
    acc += v * v;
  }
  out[gid] = acc;
}

// ---- K2: dist = xx - 2*A.B^T + yy, split-bf16 MFMA (hi*hi + hi*lo + lo*hi) ---------
__global__ __launch_bounds__(256) void k_gemm(const u16* __restrict__ Ah, const u16* __restrict__ Al,
                                              const u16* __restrict__ Bh, const u16* __restrict__ Bl,
                                              const float* __restrict__ xx, const float* __restrict__ yy,
                                              float* __restrict__ dist){
  __shared__ __align__(16) u16 lAh[128 * 64];
  __shared__ __align__(16) u16 lAl[128 * 64];
  __shared__ __align__(16) u16 lBh[128 * 64];
  __shared__ __align__(16) u16 lBl[128 * 64];
  int n0 = blockIdx.y * 128, m0 = blockIdx.x * 128;
  int t = threadIdx.x;
  f32x4 acc[4][4];
  #pragma unroll
  for (int i = 0; i < 4; i++)
    #pragma unroll
    for (int j = 0; j < 4; j++){ f32x4 z = {0.f, 0.f, 0.f, 0.f}; acc[i][j] = z; }
  int w = t >> 6, lane = t & 63, lr = lane & 15, quad = lane >> 4;
  int wn = (w >> 1) * 64, wm = (w & 1) * 64;
  for (int kt = 0; kt < 8; kt++){
    int k0 = kt * 64;
    bf16x8 vah[4], val[4], vbh[4], vbl[4];
    #pragma unroll
    for (int s = 0; s < 4; s++){
      int ch = t + 256 * s;
      int rn = ch >> 3, k8 = (ch & 7) * 8;
      size_t oa = (size_t)(n0 + rn) * CC + k0 + k8;
      size_t ob = (size_t)(m0 + rn) * CC + k0 + k8;
      vah[s] = *(const bf16x8*)(Ah + oa);
      val[s] = *(const bf16x8*)(Al + oa);
      vbh[s] = *(const bf16x8*)(Bh + ob);
      vbl[s] = *(const bf16x8*)(Bl + ob);
    }
    __syncthreads();
    #pragma unroll
    for (int s = 0; s < 4; s++){
      int ch = t + 256 * s;
      *(bf16x8*)&lAh[ch * 8] = vah[s];
      *(bf16x8*)&lAl[ch * 8] = val[s];
      *(bf16x8*)&lBh[ch * 8] = vbh[s];
      *(bf16x8*)&lBl[ch * 8] = vbl[s];
    }
    __syncthreads();
    #pragma unroll
    for (int kk = 0; kk < 2; kk++){
      int off = kk * 32 + quad * 8;
      bf16x8 afh[4], afl[4], bfh[4], bfl[4];
      #pragma unroll
      for (int i = 0; i < 4; i++){
        int ra = (wn + i * 16 + lr) * 64 + off;
        afh[i] = *(const bf16x8*)&lAh[ra];
        afl[i] = *(const bf16x8*)&lAl[ra];
      }
      #pragma unroll
      for (int j = 0; j < 4; j++){
        int rb = (wm + j * 16 + lr) * 64 + off;
        bfh[j] = *(const bf16x8*)&lBh[rb];
        bfl[j] = *(const bf16x8*)&lBl[rb];
      }
      #pragma unroll
      for (int i = 0; i < 4; i++)
        #pragma unroll
        for (int j = 0; j < 4; j++){
          acc[i][j] = __builtin_amdgcn_mfma_f32_16x16x32_bf16(afh[i], bfh[j], acc[i][j], 0, 0, 0);
          acc[i][j] = __builtin_amdgcn_mfma_f32_16x16x32_bf16(afh[i], bfl[j], acc[i][j], 0, 0, 0);
          acc[i][j] = __builtin_amdgcn_mfma_f32_16x16x32_bf16(afl[i], bfh[j], acc[i][j], 0, 0, 0);
        }
    }
  }
  #pragma unroll
  for (int i = 0; i < 4; i++){
    int nbase = n0 + wn + i * 16 + quad * 4;
    #pragma unroll
    for (int j = 0; j < 4; j++){
      int m = m0 + wm + j * 16 + lr;
      float yv = yy[m];
      #pragma unroll
      for (int r = 0; r < 4; r++){
        dist[((size_t)(nbase + r)) * MM + m] = xx[nbase + r] + yv - 2.0f * acc[i][j][r];
      }
    }
  }
}

// ---- K3: per-row min & softmax(-dist) denominator ----------------------------------
__global__ __launch_bounds__(256) void k_rowstats(const float* __restrict__ dist,
                                                  float* __restrict__ mnA, float* __restrict__ Zr){
  __shared__ float red[256];
  int row = blockIdx.x, t = threadIdx.x;
  const float* dr = dist + (size_t)row * MM;
  float d[8];
  float mn = 3.4e38f;
  #pragma unroll
  for (int i = 0; i < 8; i++){ d[i] = sane(dr[t + 256 * i]); mn = fminf(mn, d[i]); }
  mn = blockRed(mn, red, t, 1);
  float z = 0.f;
  #pragma unroll
  for (int i = 0; i < 8; i++) z += expf(mn - d[i]);
  z = blockRed(z, red, t, 0);
  if (t == 0){ mnA[row] = mn; Zr[row] = fmaxf(z, 1e-30f); }
}

// ---- K4: fused T/S/refined/rmm/src_corr/loss per row n (per batch) -----------------
__global__ __launch_bounds__(256) void k_fused(const float* __restrict__ dist, const float* __restrict__ mnA,
                                               const float* __restrict__ Zr, const int* __restrict__ sidx1b,
                                               const int* __restrict__ idx2b, const float* __restrict__ tgtb,
                                               float* __restrict__ s_corrb, float* __restrict__ lossb){
  __shared__ float Trow[MM];
  __shared__ float red[256];
  int n = blockIdx.x, t = threadIdx.x;
  const float* dn_p = dist + (size_t)n * MM;
  float dn[8];
  #pragma unroll
  for (int i = 0; i < 8; i++) dn[i] = sane(dn_p[t + 256 * i]);
  float tacc[8] = {0, 0, 0, 0, 0, 0, 0, 0};
  const int* i1 = sidx1b + n * KK1;
  for (int j = 1; j < KK1; j++){
    int r = i1[j] & 2047;
    float mnj = mnA[r];
    float izj = 1.0f / Zr[r];
    const float* drp = dist + (size_t)r * MM;
    #pragma unroll
    for (int i = 0; i < 8; i++) tacc[i] += expf(mnj - sane(drp[t + 256 * i])) * izj;
  }
  #pragma unroll
  for (int i = 0; i < 8; i++) Trow[t + 256 * i] = tacc[i];
  __syncthreads();
  float rloc[8];
  float lmin = 3.4e38f;
  #pragma unroll
  for (int i = 0; i < 8; i++){
    int m = t + 256 * i;
    const int* ip = idx2b + m * KK1;
    float S = 0.f;
    #pragma unroll
    for (int j = 1; j < KK1; j++) S += Trow[ip[j] & 2047];
    float rv = sane(expf(1.0f - S / 7.0f) * dn[i]);
    rloc[i] = rv;
    lmin = fminf(lmin, rv);
  }
  float rmin = blockRed(lmin, red, t, 1);
  float z = 0.f, s0 = 0.f, s1 = 0.f, s2 = 0.f;
  #pragma unroll
  for (int i = 0; i < 8; i++){
    int m = t + 256 * i;
    float p = expf(rmin - rloc[i]);
    z  += p;
    s0 += tgtb[0 * MM + m] * p;
    s1 += tgtb[1 * MM + m] * p;
    s2 += tgtb[2 * MM + m] * p;
  }
  z  = blockRed(z,  red, t, 0);
  s0 = blockRed(s0, red, t, 0);
  s1 = blockRed(s1, red, t, 0);
  s2 = blockRed(s2, red, t, 0);
  if (t == 0){
    float iZ = 1.0f / fmaxf(z, 1e-30f);
    s_corrb[0 * NN + n] = s0 * iZ;
    s_corrb[1 * NN + n] = s1 * iZ;
    s_corrb[2 * NN + n] = s2 * iZ;
    lossb[n] = -logf(fminf(iZ, 1.0f) + 1e-15f);  // pred at onehot == rowmax(rmm) == 1/Z
  }
}

// ---- K5: discriminator MLP, scalar f32, pure-register h (no LDS, no array) ---------
// R11 post-mortem: with Hs in LDS the scheduler SINKS the loop-invariant ds_reads
// back into the e-loop (2048 ds_read_b128/thread -> LDS-issue-bound ~41us floor).
// Fix: no memory backing for h at all -- layer-1 fully unrolled into 16 named f32x4
// registers. Per-d layer-1 arithmetic and the per-(e,q) e-loop statement stream are
// textually identical to the R10/R11-passing pattern (values & contraction-relevant
// DAG preserved; only operand storage moves to VGPRs). ~88 VGPR fits (R11 used 88).
__global__ __launch_bounds__(256) void k_disc(const float* __restrict__ s_corr, const float* __restrict__ src,
                                              const float* __restrict__ sknn, const int* __restrict__ sidx,
                                              const float* __restrict__ W1, const float* __restrict__ b1,
                                              const float* __restrict__ W2, const float* __restrict__ b2,
                                              const float* __restrict__ W3, const float* __restrict__ b3,
                                              float* __restrict__ sArr){
  int t = threadIdx.x;
  int b = blockIdx.z;
  int n = blockIdx.y * 16 + (t >> 4);
  int kk = t & 15;
  int nk = sidx[((b * NN + n) * KK) + kk] & 2047;
  float f[6];
  #pragma unroll
  for (int c = 0; c < 3; c++){
    f[c]     = s_corr[(b * 3 + c) * NN + n] - s_corr[(b * 3 + c) * NN + nk];
    f[3 + c] = src[(b * 3 + c) * NN + n] - sknn[((size_t)(b * NN + n) * KK + kk) * 3 + c];
  }
  // layer 1: per-d expressions verbatim (a = b1[d]; a += f[c]*W1[d*6+c] x6; relu)
  #define L1D(d) ({ float a_ = b1[(d)];              \
                    a_ += f[0] * W1[(d) * 6 + 0];    \
                    a_ += f[1] * W1[(d) * 6 + 1];    \
                    a_ += f[2] * W1[(d) * 6 + 2];    \
                    a_ += f[3] * W1[(d) * 6 + 3];    \
                    a_ += f[4] * W1[(d) * 6 + 4];    \
                    a_ += f[5] * W1[(d) * 6 + 5];    \
                    fmaxf(a_, 0.f); })
  #define HSET(i) f32x4 h##i;                  \
                  h##i.x = L1D(4 * (i) + 0);   \
                  h##i.y = L1D(4 * (i) + 1);   \
                  h##i.z = L1D(4 * (i) + 2);   \
                  h##i.w = L1D(4 * (i) + 3);
  HSET(0) HSET(1) HSET(2) HSET(3) HSET(4) HSET(5) HSET(6) HSET(7)
  HSET(8) HSET(9) HSET(10) HSET(11) HSET(12) HSET(13) HSET(14) HSET(15)
  #undef HSET
  #undef L1D
  float sacc = b3[0];
  for (int e = 0; e < 128; e++){
    float a = b2[e];
    const f32x4* w4 = (const f32x4*)&W2[e * 64];
    #define QSTEP(i) { f32x4 wv = w4[i]; a += wv.x * h##i.x + wv.y * h##i.y + wv.z * h##i.z + wv.w * h##i.w; }
    QSTEP(0) QSTEP(1) QSTEP(2) QSTEP(3) QSTEP(4) QSTEP(5) QSTEP(6) QSTEP(7)
    QSTEP(8) QSTEP(9) QSTEP(10) QSTEP(11) QSTEP(12) QSTEP(13) QSTEP(14) QSTEP(15)
    #undef QSTEP
    sacc += W3[e] * fmaxf(a, 0.f);
  }
  if (!(fabsf(sacc) < 1e30f)) sacc = -1e30f;
  #pragma unroll
  for (int off = 1; off < 16; off <<= 1) sacc = fmaxf(sacc, __shfl_xor(sacc, off, 16));
  if (kk == 0) sArr[b * NN + n] = sacc;
}

// ---- K6: weight = softmax(s) over n ------------------------------------------------
__global__ __launch_bounds__(256) void k_softw(const float* __restrict__ sArr, float* __restrict__ wArr){
  __shared__ float red[256];
  int b = blockIdx.x, t = threadIdx.x;
  const float* sp = sArr + b * NN;
  float sv[8];
  float mx = -3.4e38f;
  #pragma unroll
  for (int i = 0; i < 8; i++){
    float v = sp[t + 256 * i];
    if (!(fabsf(v) < 1e30f)) v = -1e30f;
    sv[i] = v; mx = fmaxf(mx, v);
  }
  mx = blockRed(mx, red, t, 2);
  float z = 0.f;
  #pragma unroll
  for (int i = 0; i < 8; i++) z += expf(sv[i] - mx);
  z = blockRed(z, red, t, 0);
  float iz = 1.0f / fmaxf(z, 1e-30f);
  #pragma unroll
  for (int i = 0; i < 8; i++) wArr[b * NN + t + 256 * i] = expf(sv[i] - mx) * iz;
}

// ---- K7: stable descending rank -> topi --------------------------------------------
__global__ __launch_bounds__(256) void k_rank(const float* __restrict__ wArr, int* __restrict__ topi){
  __shared__ float wrow[NN];
  int b = blockIdx.y, t = threadIdx.x;
  for (int i = t; i < NN; i += 256) wrow[i] = wArr[b * NN + i];
  __syncthreads();
  int n = blockIdx.x * 256 + t;
  float wn = wrow[n];
  int cnt = 0;
  for (int j = 0; j < NN; j++){
    float wj = wrow[j];
    cnt += (wj > wn) || ((wj == wn) && (j < n));
  }
  if (cnt < KEY) topi[b * KEY + cnt] = n;
}

// ---- K8: weighted centroids, H, 3x3 SVD (f64 Jacobi), R/t --------------------------
__device__ __forceinline__ double det3d(const double A[3][3]){
  return A[0][0] * (A[1][1] * A[2][2] - A[1][2] * A[2][1])
       - A[0][1] * (A[1][0] * A[2][2] - A[1][2] * A[2][0])
       + A[0][2] * (A[1][0] * A[2][1] - A[1][1] * A[2][0]);
}

__global__ __launch_bounds__(256) void k_rigid(const float* __restrict__ src, const float* __restrict__ s_corr,
                                               const float* __restrict__ wArr, float* __restrict__ Rt,
                                               float* __restrict__ out){
  __shared__ float red[256];
  int b = blockIdx.x, t = threadIdx.x;
  float wsum = 0, a0 = 0, a1 = 0, a2 = 0, c0 = 0, c1 = 0, c2 = 0;
  for (int n = t; n < NN; n += 256){
    float wv = wArr[b * NN + n];
    float s0 = src[(b * 3 + 0) * NN + n];
    float s1 = src[(b * 3 + 1) * NN + n];
    float s2 = src[(b * 3 + 2) * NN + n];
    float q0 = s_corr[(b * 3 + 0) * NN + n];
    float q1 = s_corr[(b * 3 + 1) * NN + n];
    float q2 = s_corr[(b * 3 + 2) * NN + n];
    wsum += wv; a0 += wv * s0; a1 += wv * s1; a2 += wv * s2;
    c0 += wv * q0; c1 += wv * q1; c2 += wv * q2;
  }
  wsum = blockRed(wsum, red, t, 0);
  a0 = blockRed(a0, red, t, 0); a1 = blockRed(a1, red, t, 0); a2 = blockRed(a2, red, t, 0);
  c0 = blockRed(c0, red, t, 0); c1 = blockRed(c1, red, t, 0); c2 = blockRed(c2, red, t, 0);
  float inv = 1.0f / fmaxf(wsum, 1e-30f);
  float cs0 = a0 * inv, cs1 = a1 * inv, cs2 = a2 * inv;
  float ct0 = c0 * inv, ct1 = c1 * inv, ct2 = c2 * inv;
  float h[9] = {0, 0, 0, 0, 0, 0, 0, 0, 0};
  for (int n = t; n < NN; n += 256){
    float wv = wArr[b * NN + n];
    float ds0 = src[(b * 3 + 0) * NN + n] - cs0;
    float ds1 = src[(b * 3 + 1) * NN + n] - cs1;
    float ds2 = src[(b * 3 + 2) * NN + n] - cs2;
    float dc0 = s_corr[(b * 3 + 0) * NN + n] - ct0;
    float dc1 = s_corr[(b * 3 + 1) * NN + n] - ct1;
    float dc2 = s_corr[(b * 3 + 2) * NN + n] - ct2;
    h[0] += wv * ds0 * dc0; h[1] += wv * ds0 * dc1; h[2] += wv * ds0 * dc2;
    h[3] += wv * ds1 * dc0; h[4] += wv * ds1 * dc1; h[5] += wv * ds1 * dc2;
    h[6] += wv * ds2 * dc0; h[7] += wv * ds2 * dc1; h[8] += wv * ds2 * dc2;
  }
  for (int i = 0; i < 9; i++) h[i] = blockRed(h[i], red, t, 0);
  if (t == 0){
    double Hm[3][3];
    for (int i = 0; i < 3; i++)
      for (int j = 0; j < 3; j++) Hm[i][j] = (double)h[i * 3 + j];
    double Km[3][3], V[3][3] = {{1, 0, 0}, {0, 1, 0}, {0, 0, 1}};
    for (int i = 0; i < 3; i++)
      for (int j = 0; j < 3; j++){
        double s = 0;
        for (int a = 0; a < 3; a++) s += Hm[a][i] * Hm[a][j];
        Km[i][j] = s;
      }
    double ksc = fabs(Km[0][0]) + fabs(Km[1][1]) + fabs(Km[2][2]) + 1e-300;
    for (int sweep = 0; sweep < 60; sweep++){
      int p = 0, q = 1; double mx = fabs(Km[0][1]);
      if (fabs(Km[0][2]) > mx){ mx = fabs(Km[0][2]); p = 0; q = 2; }
      if (fabs(Km[1][2]) > mx){ mx = fabs(Km[1][2]); p = 1; q = 2; }
      if (mx <= 1e-15 * ksc) break;
      double app = Km[p][p], aqq = Km[q][q], apq = Km[p][q];
      double tau = (aqq - app) / (2.0 * apq);
      double tt = ((tau >= 0) ? 1.0 : -1.0) / (fabs(tau) + sqrt(1.0 + tau * tau));
      double cc = 1.0 / sqrt(1.0 + tt * tt), sn = tt * cc;
      for (int k2 = 0; k2 < 3; k2++){
        double akp = Km[k2][p], akq = Km[k2][q];
        Km[k2][p] = cc * akp - sn * akq; Km[k2][q] = sn * akp + cc * akq;
      }
      for (int k2 = 0; k2 < 3; k2++){
        double apk = Km[p][k2], aqk = Km[q][k2];
        Km[p][k2] = cc * apk - sn * aqk; Km[q][k2] = sn * apk + cc * aqk;
      }
      for (int k2 = 0; k2 < 3; k2++){
        double vkp = V[k2][p], vkq = V[k2][q];
        V[k2][p] = cc * vkp - sn * vkq; V[k2][q] = sn * vkp + cc * vkq;
      }
    }
    double lam[3] = {Km[0][0], Km[1][1], Km[2][2]};
    int id0 = 0, id1 = 1, id2 = 2, tmp;
    if (lam[id0] < lam[id1]){ tmp = id0; id0 = id1; id1 = tmp; }
    if (lam[id0] < lam[id2]){ tmp = id0; id0 = id2; id2 = tmp; }
    if (lam[id1] < lam[id2]){ tmp = id1; id1 = id2; id2 = tmp; }
    int idx[3] = {id0, id1, id2};
    double Vs[3][3], U[3][3] = {{0, 0, 0}, {0, 0, 0}, {0, 0, 0}};
    for (int jj = 0; jj < 3; jj++){
      int j = idx[jj];
      for (int i2 = 0; i2 < 3; i2++) Vs[i2][jj] = V[i2][j];
      double u0 = 0, u1 = 0, u2 = 0;
      for (int i2 = 0; i2 < 3; i2++){
        u0 += Hm[0][i2] * V[i2][j];
        u1 += Hm[1][i2] * V[i2][j];
        u2 += Hm[2][i2] * V[i2][j];
      }
      double nrm = sqrt(u0 * u0 + u1 * u1 + u2 * u2);
      if (nrm > 1e-20){
        U[0][jj] = u0 / nrm; U[1][jj] = u1 / nrm; U[2][jj] = u2 / nrm;
      } else {
        double x0 = U[1][0] * U[2][1] - U[2][0] * U[1][1];
        double x1 = U[2][0] * U[0][1] - U[0][0] * U[2][1];
        double x2 = U[0][0] * U[1][1] - U[1][0] * U[0][1];
        double nn2 = sqrt(x0 * x0 + x1 * x1 + x2 * x2);
        if (nn2 < 1e-20){ x0 = 1; x1 = 0; x2 = 0; nn2 = 1; }
        U[0][jj] = x0 / nn2; U[1][jj] = x1 / nn2; U[2][jj] = x2 / nn2;
      }
    }
    double dd = det3d(U) * det3d(Vs);
    double Rm[3][3];
    for (int i2 = 0; i2 < 3; i2++)
      for (int k2 = 0; k2 < 3; k2++)
        Rm[i2][k2] = Vs[i2][0] * U[k2][0] + Vs[i2][1] * U[k2][1] + dd * Vs[i2][2] * U[k2][2];
    double cs[3] = {cs0, cs1, cs2}, ct[3] = {ct0, ct1, ct2};
    double tv[3];
    for (int i2 = 0; i2 < 3; i2++)
      tv[i2] = ct[i2] - (Rm[i2][0] * cs[0] + Rm[i2][1] * cs[1] + Rm[i2][2] * cs[2]);
    for (int i2 = 0; i2 < 3; i2++)
      for (int k2 = 0; k2 < 3; k2++){
        Rt[b * 12 + i2 * 3 + k2] = (float)Rm[i2][k2];
        out[b * 9 + i2 * 3 + k2] = (float)Rm[i2][k2];
      }
    for (int i2 = 0; i2 < 3; i2++){
      Rt[b * 12 + 9 + i2] = (float)tv[i2];
      out[18 + b * 3 + i2] = (float)tv[i2];
    }
  }
}

// ---- K9: src_transformed = R*src + t -----------------------------------------------
__global__ __launch_bounds__(256) void k_st(const float* __restrict__ src, const float* __restrict__ Rt,
                                            float* __restrict__ st){
  int id = blockIdx.x * 256 + threadIdx.x;
  int b = id >> 11, n = id & 2047;
  float s0 = src[(b * 3 + 0) * NN + n];
  float s1 = src[(b * 3 + 1) * NN + n];
  float s2 = src[(b * 3 + 2) * NN + n];
  const float* R = Rt + b * 12;
  #pragma unroll
  for (int c = 0; c < 3; c++)
    st[(b * 3 + c) * NN + n] = R[c * 3 + 0] * s0 + R[c * 3 + 1] * s1 + R[c * 3 + 2] * s2 + R[9 + c];
}

// ---- K10: gather keypoint outputs (float32 out) ------------------------------------
__global__ __launch_bounds__(256) void k_out(const int* __restrict__ topi, const int* __restrict__ sidx,
                                             const float* __restrict__ src, const float* __restrict__ s_corr,
                                             const float* __restrict__ st, float* __restrict__ out){
  int b = blockIdx.y, t = threadIdx.x;
  int rr = t >> 4, kk = t & 15;
  int r = blockIdx.x * 16 + rr;
  int ns = topi[b * KEY + r] & 2047;
  int nk = sidx[(b * NN + ns) * KK + kk] & 2047;
  float* o_sk  = out + 24;
  float* o_tk  = out + 6168;
  float* o_skk = out + 12312;
  float* o_tkk = out + 110616;
  #pragma unroll
  for (int c = 0; c < 3; c++){
    float cv  = s_corr[(b * 3 + c) * NN + ns];
    float ck  = s_corr[(b * 3 + c) * NN + nk];
    o_tkk[(((b * 3 + c) * KEY + r) * KK) + kk] = cv - ck;
    float sv  = st[(b * 3 + c) * NN + ns];
    float sk2 = st[(b * 3 + c) * NN + nk];
    o_skk[(((b * 3 + c) * KEY + r) * KK) + kk] = sv - sk2;
    if (kk == 0){
      o_sk[(b * 3 + c) * KEY + r] = src[(b * 3 + c) * NN + ns];
      o_tk[(b * 3 + c) * KEY + r] = cv;
    }
  }
}

// ---- K11: loss_scl -----------------------------------------------------------------
__global__ __launch_bounds__(256) void k_loss(const float* __restrict__ loss_row, const int* __restrict__ topi,
                                              float* __restrict__ out){
  __shared__ float red[256];
  int t = threadIdx.x;
  float acc = 0.f;
  for (int i = t; i < BB * KEY; i += 256){
    int b = i >> 10, r = i & 1023;
    int n = topi[b * KEY + r] & 2047;
    acc += loss_row[b * NN + n];
  }
  acc = blockRed(acc, red, t, 0);
  if (t == 0) out[208920] = acc / 2048.0f;
}

extern "C" void kernel_launch(void* const* d_in, const int* in_sizes, int n_in,
                              void* d_out, int out_size, void* d_ws, size_t ws_size,
                              hipStream_t stream){
  const float* src  = (const float*)d_in[0];
  const float* tgt  = (const float*)d_in[1];
  const float* semb = (const float*)d_in[2];
  const float* temb = (const float*)d_in[3];
  const float* sknn = (const float*)d_in[4];
  const float* W1 = (const float*)d_in[6];
  const float* b1 = (const float*)d_in[7];
  const float* W2 = (const float*)d_in[8];
  const float* b2 = (const float*)d_in[9];
  const float* W3 = (const float*)d_in[10];
  const float* b3 = (const float*)d_in[11];
  const int* sidx  = (const int*)d_in[12];
  const int* sidx1 = (const int*)d_in[13];
  const int* idx2  = (const int*)d_in[14];
  float* out = (float*)d_out;

  // workspace layout (peak ~33.4 MB)
  char* w = (char*)d_ws;
  u16* Ah = (u16*)(w);                               // 4 MB each (B,N,C) bf16 split
  u16* Al = Ah + (size_t)BB * NN * CC;
  u16* Bh = Al + (size_t)BB * NN * CC;
  u16* Bl = Bh + (size_t)BB * MM * CC;
  float* dist = (float*)(Bl + (size_t)BB * MM * CC); // 16.78 MB (N,M) f32, per-batch reuse
  char* tail = (char*)(dist + (size_t)NN * MM);
  float* xx = (float*)tail;                          // B*N
  float* yy = xx + BB * NN;                          // B*M
  float* mnA = yy + BB * MM;                         // B*N
  float* Zr = mnA + BB * NN;                         // B*N
  float* s_corr = Zr + BB * NN;                      // B*3*N
  float* loss_row = s_corr + BB * 3 * NN;            // B*N
  float* sArr = loss_row + BB * NN;                  // B*N
  float* wArr = sArr + BB * NN;                      // B*N
  int* topi = (int*)(wArr + BB * NN);                // B*KEY
  float* Rt = (float*)(topi + BB * KEY);             // B*12
  float* st = Rt + BB * 16;                          // B*3*N

  k_trans<<<dim3(16, 64, 4), dim3(32, 8), 0, stream>>>(semb, temb, Ah, Al, Bh, Bl);
  k_sq<<<dim3(16, 2), 256, 0, stream>>>(semb, temb, xx, yy);
  for (int b = 0; b < BB; b++){
    k_gemm<<<dim3(16, 16), 256, 0, stream>>>(Ah + (size_t)b * NN * CC, Al + (size_t)b * NN * CC,
                                             Bh + (size_t)b * MM * CC, Bl + (size_t)b * MM * CC,
                                             xx + b * NN, yy + b * MM, dist);
    k_rowstats<<<NN, 256, 0, stream>>>(dist, mnA + b * NN, Zr + b * NN);
    k_fused<<<NN, 256, 0, stream>>>(dist, mnA + b * NN, Zr + b * NN,
                                    sidx1 + (size_t)b * NN * KK1, idx2 + (size_t)b * MM * KK1,
                                    tgt + (size_t)b * 3 * MM, s_corr + (size_t)b * 3 * NN,
                                    loss_row + b * NN);
  }
  k_disc<<<dim3(1, 128, 2), 256, 0, stream>>>(s_corr, src, sknn, sidx, W1, b1, W2, b2, W3, b3, sArr);
  k_softw<<<BB, 256, 0, stream>>>(sArr, wArr);
  k_rank<<<dim3(8, BB), 256, 0, stream>>>(wArr, topi);
  k_rigid<<<BB, 256, 0, stream>>>(src, s_corr, wArr, Rt, out);
  k_st<<<16, 256, 0, stream>>>(src, Rt, st);
  k_out<<<dim3(64, BB), 256, 0, stream>>>(topi, sidx, src, s_corr, st, out);
  k_loss<<<1, 256, 0, stream>>>(loss_row, topi, out);
}

// Round 13
// 378.194 us; speedup vs baseline: 1.0243x; 1.0128x over previous
//
#include <hip/hip_runtime.h>
#include <stdint.h>

typedef unsigned short u16;

#define BB 2
#define NN 2048
#define MM 2048
#define CC 512
#define KK 16
#define KK1 8
#define KEY 1024

typedef __attribute__((ext_vector_type(8))) short bf16x8;
typedef __attribute__((ext_vector_type(4))) float f32x4;

__device__ __forceinline__ float b2f(u16 u){ return __uint_as_float(((uint32_t)u) << 16); }
__device__ __forceinline__ u16 f2b(float f){
  uint32_t x = __float_as_uint(f);
  uint32_t r = x + 0x7FFFu + ((x >> 16) & 1u);
  return (u16)(r >> 16);
}
__device__ __forceinline__ float sane(float v){ return (fabsf(v) < 1e30f) ? v : 1e30f; }

// all-thread block reduction, 256 threads. op: 0=sum 1=min 2=max
__device__ __forceinline__ float blockRed(float v, float* red, int t, int op){
  red[t] = v; __syncthreads();
  #pragma unroll
  for (int s = 128; s > 0; s >>= 1){
    if (t < s){
      float a = red[t], b = red[t + s];
      red[t] = (op == 0) ? (a + b) : ((op == 1) ? fminf(a, b) : fmaxf(a, b));
    }
    __syncthreads();
  }
  float r = red[0]; __syncthreads();
  return r;
}

// ---- K0: transpose f32 (B,C,N) -> split-bf16 (B,N,C) hi/lo pairs -------------------
__global__ __launch_bounds__(256) void k_trans(const float* __restrict__ semb, const float* __restrict__ temb,
                                               u16* __restrict__ Ah, u16* __restrict__ Al,
                                               u16* __restrict__ Bh, u16* __restrict__ Bl){
  __shared__ float tile[32][33];
  int b = blockIdx.z & 1, which = blockIdx.z >> 1;
  const float* in = which ? temb : semb;
  u16* oh = which ? Bh : Ah;
  u16* ol = which ? Bl : Al;
  int c0 = blockIdx.x * 32, n0 = blockIdx.y * 32;
  int tx = threadIdx.x, ty = threadIdx.y;
  #pragma unroll
  for (int i = 0; i < 4; i++){
    int r = ty + 8 * i;
    tile[r][tx] = in[((b * CC + c0 + r) * NN) + n0 + tx];
  }
  __syncthreads();
  #pragma unroll
  for (int i = 0; i < 4; i++){
    int r = ty + 8 * i;
    float v = tile[tx][r];
    u16 hi = f2b(v);
    float lo = v - b2f(hi);
    size_t o = ((size_t)(b * NN + n0 + r) * CC) + c0 + tx;
    oh[o] = hi;
    ol[o] = f2b(lo);
  }
}

// ---- K1: exact f32 row squared norms from (B,C,N) layout (coalesced over n) --------
__global__ __launch_bounds__(256) void k_sq(const float* __restrict__ semb, const float* __restrict__ temb,
                                            float* __restrict__ xx, float* __restrict__ yy){
  int which = blockIdx.y;
  const float* in = which ? temb : semb;
  float* out = which ? yy : xx;
  int gid = blockIdx.x * 256 + threadIdx.x;   // 0..4095
  int b = gid >> 11, n = gid & 2047;
  float acc = 0.f;
  for (int c = 0; c < CC; c++){
    float v = in[((size_t)(b * CC + c)) * NN + n];
    acc += v * v;
  }
  out[gid] = acc;
}

// ---- K2: dist = xx - 2*A.B^T + yy, split-bf16 MFMA (hi*hi + hi*lo + lo*hi) ---------
__global__ __launch_bounds__(256) void k_gemm(const u16* __restrict__ Ah, const u16* __restrict__ Al,
                                              const u16* __restrict__ Bh, const u16* __restrict__ Bl,
                                              const float* __restrict__ xx, const float* __restrict__ yy,
                                              float* __restrict__ dist){
  __shared__ __align__(16) u16 lAh[128 * 64];
  __shared__ __align__(16) u16 lAl[128 * 64];
  __shared__ __align__(16) u16 lBh[128 * 64];
  __shared__ __align__(16) u16 lBl[128 * 64];
  int n0 = blockIdx.y * 128, m0 = blockIdx.x * 128;
  int t = threadIdx.x;
  f32x4 acc[4][4];
  #pragma unroll
  for (int i = 0; i < 4; i++)
    #pragma unroll
    for (int j = 0; j < 4; j++){ f32x4 z = {0.f, 0.f, 0.f, 0.f}; acc[i][j] = z; }
  int w = t >> 6, lane = t & 63, lr = lane & 15, quad = lane >> 4;
  int wn = (w >> 1) * 64, wm = (w & 1) * 64;
  for (int kt = 0; kt < 8; kt++){
    int k0 = kt * 64;
    bf16x8 vah[4], val[4], vbh[4], vbl[4];
    #pragma unroll
    for (int s = 0; s < 4; s++){
      int ch = t + 256 * s;
      int rn = ch >> 3, k8 = (ch & 7) * 8;
      size_t oa = (size_t)(n0 + rn) * CC + k0 + k8;
      size_t ob = (size_t)(m0 + rn) * CC + k0 + k8;
      vah[s] = *(const bf16x8*)(Ah + oa);
      val[s] = *(const bf16x8*)(Al + oa);
      vbh[s] = *(const bf16x8*)(Bh + ob);
      vbl[s] = *(const bf16x8*)(Bl + ob);
    }
    __syncthreads();
    #pragma unroll
    for (int s = 0; s < 4; s++){
      int ch = t + 256 * s;
      *(bf16x8*)&lAh[ch * 8] = vah[s];
      *(bf16x8*)&lAl[ch * 8] = val[s];
      *(bf16x8*)&lBh[ch * 8] = vbh[s];
      *(bf16x8*)&lBl[ch * 8] = vbl[s];
    }
    __syncthreads();
    #pragma unroll
    for (int kk = 0; kk < 2; kk++){
      int off = kk * 32 + quad * 8;
      bf16x8 afh[4], afl[4], bfh[4], bfl[4];
      #pragma unroll
      for (int i = 0; i < 4; i++){
        int ra = (wn + i * 16 + lr) * 64 + off;
        afh[i] = *(const bf16x8*)&lAh[ra];
        afl[i] = *(const bf16x8*)&lAl[ra];
      }
      #pragma unroll
      for (int j = 0; j < 4; j++){
        int rb = (wm + j * 16 + lr) * 64 + off;
        bfh[j] = *(const bf16x8*)&lBh[rb];
        bfl[j] = *(const bf16x8*)&lBl[rb];
      }
      #pragma unroll
      for (int i = 0; i < 4; i++)
        #pragma unroll
        for (int j = 0; j < 4; j++){
          acc[i][j] = __builtin_amdgcn_mfma_f32_16x16x32_bf16(afh[i], bfh[j], acc[i][j], 0, 0, 0);
          acc[i][j] = __builtin_amdgcn_mfma_f32_16x16x32_bf16(afh[i], bfl[j], acc[i][j], 0, 0, 0);
          acc[i][j] = __builtin_amdgcn_mfma_f32_16x16x32_bf16(afl[i], bfh[j], acc[i][j], 0, 0, 0);
        }
    }
  }
  #pragma unroll
  for (int i = 0; i < 4; i++){
    int nbase = n0 + wn + i * 16 + quad * 4;
    #pragma unroll
    for (int j = 0; j < 4; j++){
      int m = m0 + wm + j * 16 + lr;
      float yv = yy[m];
      #pragma unroll
      for (int r = 0; r < 4; r++){
        dist[((size_t)(nbase + r)) * MM + m] = xx[nbase + r] + yv - 2.0f * acc[i][j][r];
      }
    }
  }
}

// ---- K3: per-row min & softmax(-dist) denominator ----------------------------------
__global__ __launch_bounds__(256) void k_rowstats(const float* __restrict__ dist,
                                                  float* __restrict__ mnA, float* __restrict__ Zr){
  __shared__ float red[256];
  int row = blockIdx.x, t = threadIdx.x;
  const float* dr = dist + (size_t)row * MM;
  float d[8];
  float mn = 3.4e38f;
  #pragma unroll
  for (int i = 0; i < 8; i++){ d[i] = sane(dr[t + 256 * i]); mn = fminf(mn, d[i]); }
  mn = blockRed(mn, red, t, 1);
  float z = 0.f;
  #pragma unroll
  for (int i = 0; i < 8; i++) z += expf(mn - d[i]);
  z = blockRed(z, red, t, 0);
  if (t == 0){ mnA[row] = mn; Zr[row] = fmaxf(z, 1e-30f); }
}

// ---- K4: fused T/S/refined/rmm/src_corr/loss per row n (per batch) -----------------
__global__ __launch_bounds__(256) void k_fused(const float* __restrict__ dist, const float* __restrict__ mnA,
                                               const float* __restrict__ Zr, const int* __restrict__ sidx1b,
                                               const int* __restrict__ idx2b, const float* __restrict__ tgtb,
                                               float* __restrict__ s_corrb, float* __restrict__ lossb){
  __shared__ float Trow[MM];
  __shared__ float red[256];
  int n = blockIdx.x, t = threadIdx.x;
  const float* dn_p = dist + (size_t)n * MM;
  float dn[8];
  #pragma unroll
  for (int i = 0; i < 8; i++) dn[i] = sane(dn_p[t + 256 * i]);
  float tacc[8] = {0, 0, 0, 0, 0, 0, 0, 0};
  const int* i1 = sidx1b + n * KK1;
  for (int j = 1; j < KK1; j++){
    int r = i1[j] & 2047;
    float mnj = mnA[r];
    float izj = 1.0f / Zr[r];
    const float* drp = dist + (size_t)r * MM;
    #pragma unroll
    for (int i = 0; i < 8; i++) tacc[i] += expf(mnj - sane(drp[t + 256 * i])) * izj;
  }
  #pragma unroll
  for (int i = 0; i < 8; i++) Trow[t + 256 * i] = tacc[i];
  __syncthreads();
  float rloc[8];
  float lmin = 3.4e38f;
  #pragma unroll
  for (int i = 0; i < 8; i++){
    int m = t + 256 * i;
    const int* ip = idx2b + m * KK1;
    float S = 0.f;
    #pragma unroll
    for (int j = 1; j < KK1; j++) S += Trow[ip[j] & 2047];
    float rv = sane(expf(1.0f - S / 7.0f) * dn[i]);
    rloc[i] = rv;
    lmin = fminf(lmin, rv);
  }
  float rmin = blockRed(lmin, red, t, 1);
  float z = 0.f, s0 = 0.f, s1 = 0.f, s2 = 0.f;
  #pragma unroll
  for (int i = 0; i < 8; i++){
    int m = t + 256 * i;
    float p = expf(rmin - rloc[i]);
    z  += p;
    s0 += tgtb[0 * MM + m] * p;
    s1 += tgtb[1 * MM + m] * p;
    s2 += tgtb[2 * MM + m] * p;
  }
  z  = blockRed(z,  red, t, 0);
  s0 = blockRed(s0, red, t, 0);
  s1 = blockRed(s1, red, t, 0);
  s2 = blockRed(s2, red, t, 0);
  if (t == 0){
    float iZ = 1.0f / fmaxf(z, 1e-30f);
    s_corrb[0 * NN + n] = s0 * iZ;
    s_corrb[1 * NN + n] = s1 * iZ;
    s_corrb[2 * NN + n] = s2 * iZ;
    lossb[n] = -logf(fminf(iZ, 1.0f) + 1e-15f);  // pred at onehot == rowmax(rmm) == 1/Z
  }
}

// ---- K5: discriminator MLP, scalar f32, per-thread FP stream VERBATIM from R12 -----
// R12 counters: VGPR=40, LDS=0 -> h spilled to scratch; 64KB/block working set
// thrashed L1 -> L2-bound ~59us. Changes (FP DAG untouched, integer mapping only):
//  * 64-thread blocks (4 n x 16 k), grid (1,512,2): per-CU scratch working set
//    16KB -> L1-resident reloads even if the spill persists.
//  * __launch_bounds__(64,1): max VGPR budget, best chance h stays in registers
//    (spill/fill never changes values; R9 showed launch_bounds doesn't perturb
//    contraction).
__global__ __launch_bounds__(64, 1) void k_disc(const float* __restrict__ s_corr, const float* __restrict__ src,
                                                const float* __restrict__ sknn, const int* __restrict__ sidx,
                                                const float* __restrict__ W1, const float* __restrict__ b1,
                                                const float* __restrict__ W2, const float* __restrict__ b2,
                                                const float* __restrict__ W3, const float* __restrict__ b3,
                                                float* __restrict__ sArr){
  int t = threadIdx.x;
  int b = blockIdx.z;
  int n = blockIdx.y * 4 + (t >> 4);
  int kk = t & 15;
  int nk = sidx[((b * NN + n) * KK) + kk] & 2047;
  float f[6];
  #pragma unroll
  for (int c = 0; c < 3; c++){
    f[c]     = s_corr[(b * 3 + c) * NN + n] - s_corr[(b * 3 + c) * NN + nk];
    f[3 + c] = src[(b * 3 + c) * NN + n] - sknn[((size_t)(b * NN + n) * KK + kk) * 3 + c];
  }
  // layer 1: per-d expressions verbatim (a = b1[d]; a += f[c]*W1[d*6+c] x6; relu)
  #define L1D(d) ({ float a_ = b1[(d)];              \
                    a_ += f[0] * W1[(d) * 6 + 0];    \
                    a_ += f[1] * W1[(d) * 6 + 1];    \
                    a_ += f[2] * W1[(d) * 6 + 2];    \
                    a_ += f[3] * W1[(d) * 6 + 3];    \
                    a_ += f[4] * W1[(d) * 6 + 4];    \
                    a_ += f[5] * W1[(d) * 6 + 5];    \
                    fmaxf(a_, 0.f); })
  #define HSET(i) f32x4 h##i;                  \
                  h##i.x = L1D(4 * (i) + 0);   \
                  h##i.y = L1D(4 * (i) + 1);   \
                  h##i.z = L1D(4 * (i) + 2);   \
                  h##i.w = L1D(4 * (i) + 3);
  HSET(0) HSET(1) HSET(2) HSET(3) HSET(4) HSET(5) HSET(6) HSET(7)
  HSET(8) HSET(9) HSET(10) HSET(11) HSET(12) HSET(13) HSET(14) HSET(15)
  #undef HSET
  #undef L1D
  float sacc = b3[0];
  for (int e = 0; e < 128; e++){
    float a = b2[e];
    const f32x4* w4 = (const f32x4*)&W2[e * 64];
    #define QSTEP(i) { f32x4 wv = w4[i]; a += wv.x * h##i.x + wv.y * h##i.y + wv.z * h##i.z + wv.w * h##i.w; }
    QSTEP(0) QSTEP(1) QSTEP(2) QSTEP(3) QSTEP(4) QSTEP(5) QSTEP(6) QSTEP(7)
    QSTEP(8) QSTEP(9) QSTEP(10) QSTEP(11) QSTEP(12) QSTEP(13) QSTEP(14) QSTEP(15)
    #undef QSTEP
    sacc += W3[e] * fmaxf(a, 0.f);
  }
  if (!(fabsf(sacc) < 1e30f)) sacc = -1e30f;
  #pragma unroll
  for (int off = 1; off < 16; off <<= 1) sacc = fmaxf(sacc, __shfl_xor(sacc, off, 16));
  if (kk == 0) sArr[b * NN + n] = sacc;
}

// ---- K6: weight = softmax(s) over n ------------------------------------------------
__global__ __launch_bounds__(256) void k_softw(const float* __restrict__ sArr, float* __restrict__ wArr){
  __shared__ float red[256];
  int b = blockIdx.x, t = threadIdx.x;
  const float* sp = sArr + b * NN;
  float sv[8];
  float mx = -3.4e38f;
  #pragma unroll
  for (int i = 0; i < 8; i++){
    float v = sp[t + 256 * i];
    if (!(fabsf(v) < 1e30f)) v = -1e30f;
    sv[i] = v; mx = fmaxf(mx, v);
  }
  mx = blockRed(mx, red, t, 2);
  float z = 0.f;
  #pragma unroll
  for (int i = 0; i < 8; i++) z += expf(sv[i] - mx);
  z = blockRed(z, red, t, 0);
  float iz = 1.0f / fmaxf(z, 1e-30f);
  #pragma unroll
  for (int i = 0; i < 8; i++) wArr[b * NN + t + 256 * i] = expf(sv[i] - mx) * iz;
}

// ---- K7: stable descending rank -> topi --------------------------------------------
__global__ __launch_bounds__(256) void k_rank(const float* __restrict__ wArr, int* __restrict__ topi){
  __shared__ float wrow[NN];
  int b = blockIdx.y, t = threadIdx.x;
  for (int i = t; i < NN; i += 256) wrow[i] = wArr[b * NN + i];
  __syncthreads();
  int n = blockIdx.x * 256 + t;
  float wn = wrow[n];
  int cnt = 0;
  for (int j = 0; j < NN; j++){
    float wj = wrow[j];
    cnt += (wj > wn) || ((wj == wn) && (j < n));
  }
  if (cnt < KEY) topi[b * KEY + cnt] = n;
}

// ---- K8: weighted centroids, H, 3x3 SVD (f64 Jacobi), R/t --------------------------
__device__ __forceinline__ double det3d(const double A[3][3]){
  return A[0][0] * (A[1][1] * A[2][2] - A[1][2] * A[2][1])
       - A[0][1] * (A[1][0] * A[2][2] - A[1][2] * A[2][0])
       + A[0][2] * (A[1][0] * A[2][1] - A[1][1] * A[2][0]);
}

__global__ __launch_bounds__(256) void k_rigid(const float* __restrict__ src, const float* __restrict__ s_corr,
                                               const float* __restrict__ wArr, float* __restrict__ Rt,
                                               float* __restrict__ out){
  __shared__ float red[256];
  int b = blockIdx.x, t = threadIdx.x;
  float wsum = 0, a0 = 0, a1 = 0, a2 = 0, c0 = 0, c1 = 0, c2 = 0;
  for (int n = t; n < NN; n += 256){
    float wv = wArr[b * NN + n];
    float s0 = src[(b * 3 + 0) * NN + n];
    float s1 = src[(b * 3 + 1) * NN + n];
    float s2 = src[(b * 3 + 2) * NN + n];
    float q0 = s_corr[(b * 3 + 0) * NN + n];
    float q1 = s_corr[(b * 3 + 1) * NN + n];
    float q2 = s_corr[(b * 3 + 2) * NN + n];
    wsum += wv; a0 += wv * s0; a1 += wv * s1; a2 += wv * s2;
    c0 += wv * q0; c1 += wv * q1; c2 += wv * q2;
  }
  wsum = blockRed(wsum, red, t, 0);
  a0 = blockRed(a0, red, t, 0); a1 = blockRed(a1, red, t, 0); a2 = blockRed(a2, red, t, 0);
  c0 = blockRed(c0, red, t, 0); c1 = blockRed(c1, red, t, 0); c2 = blockRed(c2, red, t, 0);
  float inv = 1.0f / fmaxf(wsum, 1e-30f);
  float cs0 = a0 * inv, cs1 = a1 * inv, cs2 = a2 * inv;
  float ct0 = c0 * inv, ct1 = c1 * inv, ct2 = c2 * inv;
  float h[9] = {0, 0, 0, 0, 0, 0, 0, 0, 0};
  for (int n = t; n < NN; n += 256){
    float wv = wArr[b * NN + n];
    float ds0 = src[(b * 3 + 0) * NN + n] - cs0;
    float ds1 = src[(b * 3 + 1) * NN + n] - cs1;
    float ds2 = src[(b * 3 + 2) * NN + n] - cs2;
    float dc0 = s_corr[(b * 3 + 0) * NN + n] - ct0;
    float dc1 = s_corr[(b * 3 + 1) * NN + n] - ct1;
    float dc2 = s_corr[(b * 3 + 2) * NN + n] - ct2;
    h[0] += wv * ds0 * dc0; h[1] += wv * ds0 * dc1; h[2] += wv * ds0 * dc2;
    h[3] += wv * ds1 * dc0; h[4] += wv * ds1 * dc1; h[5] += wv * ds1 * dc2;
    h[6] += wv * ds2 * dc0; h[7] += wv * ds2 * dc1; h[8] += wv * ds2 * dc2;
  }
  for (int i = 0; i < 9; i++) h[i] = blockRed(h[i], red, t, 0);
  if (t == 0){
    double Hm[3][3];
    for (int i = 0; i < 3; i++)
      for (int j = 0; j < 3; j++) Hm[i][j] = (double)h[i * 3 + j];
    double Km[3][3], V[3][3] = {{1, 0, 0}, {0, 1, 0}, {0, 0, 1}};
    for (int i = 0; i < 3; i++)
      for (int j = 0; j < 3; j++){
        double s = 0;
        for (int a = 0; a < 3; a++) s += Hm[a][i] * Hm[a][j];
        Km[i][j] = s;
      }
    double ksc = fabs(Km[0][0]) + fabs(Km[1][1]) + fabs(Km[2][2]) + 1e-300;
    for (int sweep = 0; sweep < 60; sweep++){
      int p = 0, q = 1; double mx = fabs(Km[0][1]);
      if (fabs(Km[0][2]) > mx){ mx = fabs(Km[0][2]); p = 0; q = 2; }
      if (fabs(Km[1][2]) > mx){ mx = fabs(Km[1][2]); p = 1; q = 2; }
      if (mx <= 1e-15 * ksc) break;
      double app = Km[p][p], aqq = Km[q][q], apq = Km[p][q];
      double tau = (aqq - app) / (2.0 * apq);
      double tt = ((tau >= 0) ? 1.0 : -1.0) / (fabs(tau) + sqrt(1.0 + tau * tau));
      double cc = 1.0 / sqrt(1.0 + tt * tt), sn = tt * cc;
      for (int k2 = 0; k2 < 3; k2++){
        double akp = Km[k2][p], akq = Km[k2][q];
        Km[k2][p] = cc * akp - sn * akq; Km[k2][q] = sn * akp + cc * akq;
      }
      for (int k2 = 0; k2 < 3; k2++){
        double apk = Km[p][k2], aqk = Km[q][k2];
        Km[p][k2] = cc * apk - sn * aqk; Km[q][k2] = sn * apk + cc * aqk;
      }
      for (int k2 = 0; k2 < 3; k2++){
        double vkp = V[k2][p], vkq = V[k2][q];
        V[k2][p] = cc * vkp - sn * vkq; V[k2][q] = sn * vkp + cc * vkq;
      }
    }
    double lam[3] = {Km[0][0], Km[1][1], Km[2][2]};
    int id0 = 0, id1 = 1, id2 = 2, tmp;
    if (lam[id0] < lam[id1]){ tmp = id0; id0 = id1; id1 = tmp; }
    if (lam[id0] < lam[id2]){ tmp = id0; id0 = id2; id2 = tmp; }
    if (lam[id1] < lam[id2]){ tmp = id1; id1 = id2; id2 = tmp; }
    int idx[3] = {id0, id1, id2};
    double Vs[3][3], U[3][3] = {{0, 0, 0}, {0, 0, 0}, {0, 0, 0}};
    for (int jj = 0; jj < 3; jj++){
      int j = idx[jj];
      for (int i2 = 0; i2 < 3; i2++) Vs[i2][jj] = V[i2][j];
      double u0 = 0, u1 = 0, u2 = 0;
      for (int i2 = 0; i2 < 3; i2++){
        u0 += Hm[0][i2] * V[i2][j];
        u1 += Hm[1][i2] * V[i2][j];
        u2 += Hm[2][i2] * V[i2][j];
      }
      double nrm = sqrt(u0 * u0 + u1 * u1 + u2 * u2);
      if (nrm > 1e-20){
        U[0][jj] = u0 / nrm; U[1][jj] = u1 / nrm; U[2][jj] = u2 / nrm;
      } else {
        double x0 = U[1][0] * U[2][1] - U[2][0] * U[1][1];
        double x1 = U[2][0] * U[0][1] - U[0][0] * U[2][1];
        double x2 = U[0][0] * U[1][1] - U[1][0] * U[0][1];
        double nn2 = sqrt(x0 * x0 + x1 * x1 + x2 * x2);
        if (nn2 < 1e-20){ x0 = 1; x1 = 0; x2 = 0; nn2 = 1; }
        U[0][jj] = x0 / nn2; U[1][jj] = x1 / nn2; U[2][jj] = x2 / nn2;
      }
    }
    double dd = det3d(U) * det3d(Vs);
    double Rm[3][3];
    for (int i2 = 0; i2 < 3; i2++)
      for (int k2 = 0; k2 < 3; k2++)
        Rm[i2][k2] = Vs[i2][0] * U[k2][0] + Vs[i2][1] * U[k2][1] + dd * Vs[i2][2] * U[k2][2];
    double cs[3] = {cs0, cs1, cs2}, ct[3] = {ct0, ct1, ct2};
    double tv[3];
    for (int i2 = 0; i2 < 3; i2++)
      tv[i2] = ct[i2] - (Rm[i2][0] * cs[0] + Rm[i2][1] * cs[1] + Rm[i2][2] * cs[2]);
    for (int i2 = 0; i2 < 3; i2++)
      for (int k2 = 0; k2 < 3; k2++){
        Rt[b * 12 + i2 * 3 + k2] = (float)Rm[i2][k2];
        out[b * 9 + i2 * 3 + k2] = (float)Rm[i2][k2];
      }
    for (int i2 = 0; i2 < 3; i2++){
      Rt[b * 12 + 9 + i2] = (float)tv[i2];
      out[18 + b * 3 + i2] = (float)tv[i2];
    }
  }
}

// ---- K10: gather keypoint outputs, with src_transformed fused inline ---------------
// (k_st eliminated: st values computed at the gathered indices with the identical
// expression R[c*3+0]*s0 + R[c*3+1]*s1 + R[c*3+2]*s2 + R[9+c] -> bitwise-same out)
__global__ __launch_bounds__(256) void k_out(const int* __restrict__ topi, const int* __restrict__ sidx,
                                             const float* __restrict__ src, const float* __restrict__ s_corr,
                                             const float* __restrict__ Rt, float* __restrict__ out){
  int b = blockIdx.y, t = threadIdx.x;
  int rr = t >> 4, kk = t & 15;
  int r = blockIdx.x * 16 + rr;
  int ns = topi[b * KEY + r] & 2047;
  int nk = sidx[(b * NN + ns) * KK + kk] & 2047;
  const float* R = Rt + b * 12;
  float sns0 = src[(b * 3 + 0) * NN + ns];
  float sns1 = src[(b * 3 + 1) * NN + ns];
  float sns2 = src[(b * 3 + 2) * NN + ns];
  float snk0 = src[(b * 3 + 0) * NN + nk];
  float snk1 = src[(b * 3 + 1) * NN + nk];
  float snk2 = src[(b * 3 + 2) * NN + nk];
  float* o_sk  = out + 24;
  float* o_tk  = out + 6168;
  float* o_skk = out + 12312;
  float* o_tkk = out + 110616;
  #pragma unroll
  for (int c = 0; c < 3; c++){
    float cv  = s_corr[(b * 3 + c) * NN + ns];
    float ck  = s_corr[(b * 3 + c) * NN + nk];
    o_tkk[(((b * 3 + c) * KEY + r) * KK) + kk] = cv - ck;
    float sv  = R[c * 3 + 0] * sns0 + R[c * 3 + 1] * sns1 + R[c * 3 + 2] * sns2 + R[9 + c];
    float sk2 = R[c * 3 + 0] * snk0 + R[c * 3 + 1] * snk1 + R[c * 3 + 2] * snk2 + R[9 + c];
    o_skk[(((b * 3 + c) * KEY + r) * KK) + kk] = sv - sk2;
    if (kk == 0){
      o_sk[(b * 3 + c) * KEY + r] = sns0 * (c == 0) + sns1 * (c == 1) + sns2 * (c == 2);
      o_tk[(b * 3 + c) * KEY + r] = cv;
    }
  }
}

// ---- K11: loss_scl -----------------------------------------------------------------
__global__ __launch_bounds__(256) void k_loss(const float* __restrict__ loss_row, const int* __restrict__ topi,
                                              float* __restrict__ out){
  __shared__ float red[256];
  int t = threadIdx.x;
  float acc = 0.f;
  for (int i = t; i < BB * KEY; i += 256){
    int b = i >> 10, r = i & 1023;
    int n = topi[b * KEY + r] & 2047;
    acc += loss_row[b * NN + n];
  }
  acc = blockRed(acc, red, t, 0);
  if (t == 0) out[208920] = acc / 2048.0f;
}

extern "C" void kernel_launch(void* const* d_in, const int* in_sizes, int n_in,
                              void* d_out, int out_size, void* d_ws, size_t ws_size,
                              hipStream_t stream){
  const float* src  = (const float*)d_in[0];
  const float* tgt  = (const float*)d_in[1];
  const float* semb = (const float*)d_in[2];
  const float* temb = (const float*)d_in[3];
  const float* sknn = (const float*)d_in[4];
  const float* W1 = (const float*)d_in[6];
  const float* b1 = (const float*)d_in[7];
  const float* W2 = (const float*)d_in[8];
  const float* b2 = (const float*)d_in[9];
  const float* W3 = (const float*)d_in[10];
  const float* b3 = (const float*)d_in[11];
  const int* sidx  = (const int*)d_in[12];
  const int* sidx1 = (const int*)d_in[13];
  const int* idx2  = (const int*)d_in[14];
  float* out = (float*)d_out;

  // workspace layout (peak ~33.4 MB)
  char* w = (char*)d_ws;
  u16* Ah = (u16*)(w);                               // 4 MB each (B,N,C) bf16 split
  u16* Al = Ah + (size_t)BB * NN * CC;
  u16* Bh = Al + (size_t)BB * NN * CC;
  u16* Bl = Bh + (size_t)BB * MM * CC;
  float* dist = (float*)(Bl + (size_t)BB * MM * CC); // 16.78 MB (N,M) f32, per-batch reuse
  char* tail = (char*)(dist + (size_t)NN * MM);
  float* xx = (float*)tail;                          // B*N
  float* yy = xx + BB * NN;                          // B*M
  float* mnA = yy + BB * MM;                         // B*N
  float* Zr = mnA + BB * NN;                         // B*N
  float* s_corr = Zr + BB * NN;                      // B*3*N
  float* loss_row = s_corr + BB * 3 * NN;            // B*N
  float* sArr = loss_row + BB * NN;                  // B*N
  float* wArr = sArr + BB * NN;                      // B*N
  int* topi = (int*)(wArr + BB * NN);                // B*KEY
  float* Rt = (float*)(topi + BB * KEY);             // B*12

  k_trans<<<dim3(16, 64, 4), dim3(32, 8), 0, stream>>>(semb, temb, Ah, Al, Bh, Bl);
  k_sq<<<dim3(16, 2), 256, 0, stream>>>(semb, temb, xx, yy);
  for (int b = 0; b < BB; b++){
    k_gemm<<<dim3(16, 16), 256, 0, stream>>>(Ah + (size_t)b * NN * CC, Al + (size_t)b * NN * CC,
                                             Bh + (size_t)b * MM * CC, Bl + (size_t)b * MM * CC,
                                             xx + b * NN, yy + b * MM, dist);
    k_rowstats<<<NN, 256, 0, stream>>>(dist, mnA + b * NN, Zr + b * NN);
    k_fused<<<NN, 256, 0, stream>>>(dist, mnA + b * NN, Zr + b * NN,
                                    sidx1 + (size_t)b * NN * KK1, idx2 + (size_t)b * MM * KK1,
                                    tgt + (size_t)b * 3 * MM, s_corr + (size_t)b * 3 * NN,
                                    loss_row + b * NN);
  }
  k_disc<<<dim3(1, 512, 2), 64, 0, stream>>>(s_corr, src, sknn, sidx, W1, b1, W2, b2, W3, b3, sArr);
  k_softw<<<BB, 256, 0, stream>>>(sArr, wArr);
  k_rank<<<dim3(8, BB), 256, 0, stream>>>(wArr, topi);
  k_rigid<<<BB, 256, 0, stream>>>(src, s_corr, wArr, Rt, out);
  k_out<<<dim3(64, BB), 256, 0, stream>>>(topi, sidx, src, s_corr, Rt, out);
  k_loss<<<1, 256, 0, stream>>>(loss_row, topi, out);
}